// Round 14
// baseline (3744.019 us; speedup 1.0000x reference)
//
#include <hip/hip_runtime.h>

// ---------------------------------------------------------------------------
// PointNet++ (defense variant) forward on MI355X.
// B=8, N=4096 -> 2048 -> 512, K=32 neighbors. Geometry is EXACT: positions are
// multiples of 2^-23 (f64 knn d2 / i64 fps d2 are exact) — discrete choices
// match an np-f64 reference exactly.
// R14: paired-winner FPS. Carry TOP-2 keys through the DPP reduce
// (bound_ctrl=1: invalid lanes -> identity 0, avoiding max-duplication).
// With global (K1,K2): winner w1 = idx(K1); since all other keys < K2 and
// updates only decrease keys, next winner == idx(K2) exactly iff
// d2(idx(K2), w1) >= (K2>>12). When it holds, commit 2 winners per barrier
// round (fused 2-distance update) — ~1850 cyc saved per paired round vs
// ~+480 cyc/round top-2 overhead. Exactness preserved (absmax 0 check).
// ---------------------------------------------------------------------------

#define NB 8

__device__ __forceinline__ unsigned obits(float f) {
  unsigned u = __float_as_uint(f);
  return (u & 0x80000000u) ? ~u : (u | 0x80000000u);
}

static constexpr int CAND = 1024;

// ---------------- DPP helpers (VALU cross-lane, no LDS pipe) ----------------
// mov with bound_ctrl=1: invalid source -> 0 (identity for unsigned max).
template<int CTRL>
__device__ __forceinline__ unsigned long long dpp_mov0_u64(unsigned long long v) {
  const int lo = (int)(unsigned)(v & 0xffffffffull);
  const int hi = (int)(unsigned)(v >> 32);
  const unsigned nlo = (unsigned)__builtin_amdgcn_update_dpp(0, lo, CTRL, 0xf, 0xf, true);
  const unsigned nhi = (unsigned)__builtin_amdgcn_update_dpp(0, hi, CTRL, 0xf, 0xf, true);
  return ((unsigned long long)nhi << 32) | nlo;
}

// wave64 inclusive prefix-sum (gfx9 DPP idiom; correctness-verified R9)
__device__ __forceinline__ unsigned wave_iscan_add(unsigned x) {
  x += (unsigned)__builtin_amdgcn_update_dpp(0, (int)x, 0x111, 0xf, 0xf, true); // shr1
  x += (unsigned)__builtin_amdgcn_update_dpp(0, (int)x, 0x112, 0xf, 0xf, true); // shr2
  x += (unsigned)__builtin_amdgcn_update_dpp(0, (int)x, 0x114, 0xf, 0xf, true); // shr4
  x += (unsigned)__builtin_amdgcn_update_dpp(0, (int)x, 0x118, 0xf, 0xf, true); // shr8
  x += (unsigned)__builtin_amdgcn_update_dpp(0, (int)x, 0x142, 0xa, 0xf, true); // bcast15
  x += (unsigned)__builtin_amdgcn_update_dpp(0, (int)x, 0x143, 0xc, 0xf, true); // bcast31
  return x;
}

__device__ __forceinline__ unsigned long long u64max(unsigned long long a,
                                                    unsigned long long b) {
  return (b > a) ? b : a;
}
__device__ __forceinline__ unsigned long long u64min(unsigned long long a,
                                                    unsigned long long b) {
  return (b < a) ? b : a;
}

__device__ __forceinline__ void set_wave_prio_hi() {
#if __has_builtin(__builtin_amdgcn_s_setprio)
  __builtin_amdgcn_s_setprio(3);
#endif
}

// ---------------- FPS body (exact integer keys, paired-winner rounds) -------
// key = (d2 << 12) | (4095 - j)  =>  max key == (max d2, tie -> min j).
template<int N, int NOUT, int T>
__device__ __forceinline__ void fps_body(char* sm, const float* __restrict__ pb,
                                         int* __restrict__ fi, int b) {
  constexpr int P = N / T;
  constexpr int NW = T / 64;
  int4* sPosI = (int4*)sm;                                   // [N]
  int*  sfi   = (int*)(sm + (size_t)N * 16);                 // [NOUT]
  ulonglong2* sKey =
      (ulonglong2*)(sm + (size_t)N * 16 + NOUT * 4);         // [2][NW]
  const int tid = threadIdx.x, wid = tid >> 6, lane = tid & 63;
  set_wave_prio_hi();    // protect the serial chain from co-resident waves
  int ix[P], iy[P], iz[P];
  unsigned long long mind[P];
  for (int t = tid; t < N; t += T) {
    sPosI[t] = make_int4((int)(pb[3*t]   * 8388608.f),   // exact: 2^-23 multiples
                         (int)(pb[3*t+1] * 8388608.f),
                         (int)(pb[3*t+2] * 8388608.f), 0);
  }
  __syncthreads();
  const int x0 = sPosI[0].x, y0 = sPosI[0].y, z0 = sPosI[0].z;
  const int invBase = 4095 - tid * P;
  unsigned long long bv1, bv2;
  {
    unsigned long long tv[P];
#pragma unroll
    for (int e = 0; e < P; e++) {
      const int j = tid * P + e;
      const int4 p4 = sPosI[j];
      ix[e] = p4.x; iy[e] = p4.y; iz[e] = p4.z;
      const long long dx = p4.x - x0, dy = p4.y - y0, dz = p4.z - z0;
      const unsigned long long d2 =
          (unsigned long long)(dx * dx + dy * dy + dz * dz);   // exact, < 2^48
      const unsigned long long k = (d2 << 12) | (unsigned)(invBase - e);
      mind[e] = k; tv[e] = k;
    }
#pragma unroll
    for (int s = 1; s < P; s <<= 1)
#pragma unroll
      for (int e = 0; e + s < P; e += 2 * s)
        tv[e] = u64max(tv[e], tv[e + s]);
    bv1 = tv[0];
    unsigned long long s2 = 0ull;
#pragma unroll
    for (int e = 0; e < P; e++)
      s2 = u64max(s2, (mind[e] == bv1) ? 0ull : mind[e]);   // keys are unique
    bv2 = s2;
  }
  if (tid == 0) sfi[0] = 0;
  int t = 1, pp = 0;
  while (t < NOUT) {
    // wave top-2 DPP reduce: merge (a1>=a2) with moved (o1,o2)
    unsigned long long a1 = bv1, a2 = bv2;
#define TOP2_STEP(CTRL)                                                   \
    {                                                                     \
      const unsigned long long o1 = dpp_mov0_u64<CTRL>(a1);               \
      const unsigned long long o2 = dpp_mov0_u64<CTRL>(a2);               \
      const unsigned long long n1 = u64max(a1, o1);                       \
      const unsigned long long n2 = u64max(u64min(a1, o1), u64max(a2, o2)); \
      a1 = n1; a2 = n2;                                                   \
    }
    TOP2_STEP(0x111)   // row_shr:1
    TOP2_STEP(0x112)   // row_shr:2
    TOP2_STEP(0x114)   // row_shr:4
    TOP2_STEP(0x118)   // row_shr:8
    TOP2_STEP(0x142)   // row_bcast:15
    TOP2_STEP(0x143)   // row_bcast:31
#undef TOP2_STEP
    if (lane == 63) sKey[pp * NW + wid] = make_ulonglong2(a1, a2);
    __syncthreads();   // only barrier per round; LDS-only (no vmcnt drain)
    // pairwise-tree merge of the NW wave top-2 pairs
    ulonglong2 kv[NW];
#pragma unroll
    for (int w2 = 0; w2 < NW; w2++) kv[w2] = sKey[pp * NW + w2];
#pragma unroll
    for (int s = 1; s < NW; s <<= 1)
#pragma unroll
      for (int w2 = 0; w2 + s < NW; w2 += 2 * s) {
        const unsigned long long n1 = u64max(kv[w2].x, kv[w2 + s].x);
        const unsigned long long n2 =
            u64max(u64min(kv[w2].x, kv[w2 + s].x), u64max(kv[w2].y, kv[w2 + s].y));
        kv[w2] = make_ulonglong2(n1, n2);
      }
    const unsigned long long K1 = kv[0].x, K2 = kv[0].y;
    const int w1 = 4095 - (int)(K1 & 0xFFFull);
    const int4 c1 = sPosI[w1];                 // b128 same-address broadcast
    const int r  = 4095 - (int)(K2 & 0xFFFull);
    const int4 c2 = sPosI[r];
    // exact pairing condition: d2(r, w1) >= mind_r  (all threads redundantly)
    const long long rdx = c2.x - c1.x, rdy = c2.y - c1.y, rdz = c2.z - c1.z;
    const unsigned long long d2rw =
        (unsigned long long)(rdx * rdx + rdy * rdy + rdz * rdz);
    const bool paired = (t + 1 < NOUT) && (d2rw >= (K2 >> 12));
    if (tid == 0) {
      sfi[t] = w1;
      if (paired) sfi[t + 1] = r;
    }
    unsigned long long tv[P];
    if (paired) {
#pragma unroll
      for (int e = 0; e < P; e++) {
        const long long dx = ix[e] - c1.x, dy = iy[e] - c1.y, dz = iz[e] - c1.z;
        const long long ex = ix[e] - c2.x, ey = iy[e] - c2.y, ez = iz[e] - c2.z;
        const unsigned long long nd1 =
            (unsigned long long)(dx * dx + dy * dy + dz * dz);
        const unsigned long long nd2 =
            (unsigned long long)(ex * ex + ey * ey + ez * ez);
        const unsigned long long nd = u64min(nd1, nd2);
        const unsigned long long nk = (nd << 12) | (unsigned)(invBase - e);
        const unsigned long long mk = u64min(mind[e], nk);
        mind[e] = mk; tv[e] = mk;
      }
    } else {
#pragma unroll
      for (int e = 0; e < P; e++) {
        const long long dx = ix[e] - c1.x, dy = iy[e] - c1.y, dz = iz[e] - c1.z;
        const unsigned long long nd =
            (unsigned long long)(dx * dx + dy * dy + dz * dz);
        const unsigned long long nk = (nd << 12) | (unsigned)(invBase - e);
        const unsigned long long mk = u64min(mind[e], nk);
        mind[e] = mk; tv[e] = mk;
      }
    }
#pragma unroll
    for (int s = 1; s < P; s <<= 1)
#pragma unroll
      for (int e = 0; e + s < P; e += 2 * s)
        tv[e] = u64max(tv[e], tv[e + s]);
    bv1 = tv[0];
    unsigned long long s2 = 0ull;
#pragma unroll
    for (int e = 0; e < P; e++)
      s2 = u64max(s2, (mind[e] == bv1) ? 0ull : mind[e]);
    bv2 = s2;
    t += paired ? 2 : 1;
    pp ^= 1;
  }
  __syncthreads();
  for (int t2 = tid; t2 < NOUT; t2 += T) fi[(size_t)b * NOUT + t2] = sfi[t2];
}

// ---------------- knn (exact f64 top-32, LDS d2s) + conv fused per row ------
// FOLDMAX: atomicMax post-relu (>= 0; IEEE bits int-order-isomorphic) into
// feat[b][c] (global max pool) instead of storing out rows.
template<int N, int H, int C, bool HASX, bool FOLDMAX, int T>
__device__ __forceinline__ void knnconv_body(
    char* sm, const float* __restrict__ pb, int b, int i,
    const float* __restrict__ U, const float* __restrict__ Wrel,
    const float* __restrict__ b1, const float* __restrict__ W2,
    const float* __restrict__ b2, float* __restrict__ out, double rr) {
  constexpr int HCHUNK = (C == 64) ? 64 : (C == 128 ? 32 : 16);
  constexpr int STR = HCHUNK + 4;
  constexpr int NW = T / 64;        // k-groups
  constexpr int EPK = 32 / NW;      // k's per thread
  constexpr int BPT = 2048 / T;     // histogram bins per thread
  constexpr int KNNFRONT = N * 8 + 13312;
  constexpr int CONVFRONT = 32 * H * 4 + C * STR * 4 + NW * C * 4;
  constexpr int FRONT = (KNNFRONT > CONVFRONT) ? KNNFRONT : CONVFRONT;
  // knn views
  double*   d2s     = (double*)sm;                        // [N]
  unsigned* hist    = (unsigned*)(sm + N * 8);            // [2048]
  int*      candIdx = (int*)(sm + N * 8 + 8192);          // [CAND]
  unsigned* sWT     = (unsigned*)(sm + N * 8 + 12288);    // [NW]
  // conv views (alias the knn front; born after ranking completes)
  float* h1s  = (float*)sm;                               // [32*H]
  float* sW2T = (float*)(sm + 32 * H * 4);                // [C*STR]
  float* sRed = (float*)(sm + 32 * H * 4 + C * STR * 4);  // [NW][C]
  // tail (never aliased)
  int*   snbr = (int*)(sm + FRONT);                       // [32]
  float* rel  = (float*)(sm + FRONT + 128);               // [32][3]
  int*   pcnt = (int*)(sm + FRONT + 128 + 384);
  int*   pbin = pcnt + 1;
  const int tid = threadIdx.x;

  // --- distance pass: exact f64 d2 into LDS ---
  const double xi = pb[3*i], yi = pb[3*i+1], zi = pb[3*i+2];
  const double si = (xi*xi + yi*yi) + zi*zi;
  for (int t = tid; t < 2048; t += T) hist[t] = 0u;
  if (tid == 0) *pcnt = 0;
  __syncthreads();
  for (int j = tid; j < N; j += T) {
    double xj = pb[3*j], yj = pb[3*j+1], zj = pb[3*j+2];
    double sj = (xj*xj + yj*yj) + zj*zj;
    double dt = (xi*xj + yi*yj) + zi*zj;
    double d2 = (si + sj) - 2.0*dt;       // exact in f64
    if (j == i) d2 += 1e9;                // self-exclusion
    d2s[j] = d2;
    atomicAdd(&hist[obits((float)d2) >> 21], 1u);
  }
  __syncthreads();
  // --- bin threshold via DPP scan ---
  unsigned lsum = 0;
  const int base = tid * BPT;
#pragma unroll
  for (int q = 0; q < BPT; q++) lsum += hist[base + q];
  const unsigned isc = wave_iscan_add(lsum);
  if ((tid & 63) == 63) sWT[tid >> 6] = isc;
  __syncthreads();
  {
    const int wid = tid >> 6;
    unsigned offs = 0;
#pragma unroll
    for (int w2 = 0; w2 < NW; w2++) offs += (w2 < wid) ? sWT[w2] : 0u;
    const unsigned incl = isc + offs, excl = incl - lsum;
    if (excl < 32u && incl >= 32u) {
      unsigned c = excl;
      for (int q = 0; q < BPT; q++) {
        c += hist[base + q];
        if (c >= 32u) { *pbin = base + q; break; }
      }
    }
  }
  __syncthreads();
  const int binT = *pbin;
  for (int j = tid; j < N; j += T) {
    if ((int)(obits((float)d2s[j]) >> 21) <= binT) {
      int p = atomicAdd(pcnt, 1);
      if (p < CAND) candIdx[p] = j;
    }
  }
  __syncthreads();
  const int M = min(*pcnt, CAND);   // true top-32 superset (proxy monotone)
  for (int c = tid; c < M; c += T) {
    const int j = candIdx[c];
    const double d = d2s[j];
    int rank = 0;
    for (int e = 0; e < M; e++) {
      const int j2 = candIdx[e];
      const double de = d2s[j2];
      rank += (de < d || (de == d && j2 < j)) ? 1 : 0;
    }
    if (rank < 32) snbr[rank] = (d <= rr) ? j : -1;
  }
  __syncthreads();                 // knn LDS dead from here; snbr valid

  // --- rel ---
  if (tid < 32) {
    const int j = snbr[tid];
    float rx = 0.f, ry = 0.f, rz = 0.f;
    if (j >= 0) {
      rx = pb[3*j]   - pb[3*i];
      ry = pb[3*j+1] - pb[3*i+1];
      rz = pb[3*j+2] - pb[3*i+2];
    }
    rel[tid*3+0] = rx; rel[tid*3+1] = ry; rel[tid*3+2] = rz;
  }
  __syncthreads();

  // --- conv phase B: h1[k][h0..h0+3] = relu(U[j] (+b1) + rel . Wrel) ---
  constexpr int QPK = H / 4;
  for (int qi = tid; qi < 32 * QPK; qi += T) {
    const int k = qi / QPK, h0 = (qi - k * QPK) * 4;
    const int j = snbr[k];
    float4 v = make_float4(0.f, 0.f, 0.f, 0.f);
    if (j >= 0) {
      float4 a = HASX ? *(const float4*)&U[((size_t)b * N + j) * H + h0]
                      : *(const float4*)&b1[h0];
      const float rx = rel[k*3], ry = rel[k*3+1], rz = rel[k*3+2];
      const float4 w0 = *(const float4*)&Wrel[h0];
      const float4 w1 = *(const float4*)&Wrel[H + h0];
      const float4 w2 = *(const float4*)&Wrel[2 * H + h0];
      a.x += rx * w0.x + ry * w1.x + rz * w2.x;
      a.y += rx * w0.y + ry * w1.y + rz * w2.y;
      a.z += rx * w0.z + ry * w1.z + rz * w2.z;
      a.w += rx * w0.w + ry * w1.w + rz * w2.w;
      v = make_float4(fmaxf(a.x, 0.f), fmaxf(a.y, 0.f),
                      fmaxf(a.z, 0.f), fmaxf(a.w, 0.f));
    }
    *(float4*)&h1s[k * H + h0] = v;
  }
  const int cc = tid & 63;
  const int kk = tid >> 6;          // 0..NW-1
  constexpr int CC = C / 64;
  float acc[EPK][CC];
#pragma unroll
  for (int e = 0; e < EPK; e++)
#pragma unroll
    for (int q = 0; q < CC; q++) acc[e][q] = 0.f;
  // --- conv phase C: h2 = h1 @ W2 (W2 staged transposed+padded) ---
  for (int hc = 0; hc < H; hc += HCHUNK) {
    __syncthreads();
    for (int idx = tid; idx < HCHUNK * C; idx += T) {
      const int hh = idx / C, c = idx - hh * C;
      sW2T[c * STR + hh] = W2[(size_t)(hc + hh) * C + c];
    }
    __syncthreads();
    for (int hh0 = 0; hh0 < HCHUNK; hh0 += 4) {
      float4 wv[CC];
#pragma unroll
      for (int q = 0; q < CC; q++)
        wv[q] = *(const float4*)&sW2T[(cc + q * 64) * STR + hh0];
#pragma unroll
      for (int e = 0; e < EPK; e++) {
        const float4 hv = *(const float4*)&h1s[(kk + e * NW) * H + hc + hh0];
#pragma unroll
        for (int q = 0; q < CC; q++) {
          acc[e][q] += hv.x * wv[q].x;
          acc[e][q] += hv.y * wv[q].y;
          acc[e][q] += hv.z * wv[q].z;
          acc[e][q] += hv.w * wv[q].w;
        }
      }
    }
  }
  // --- masked max over k, +b2, relu ---
  float m[CC];
#pragma unroll
  for (int q = 0; q < CC; q++) m[q] = -1e9f;
#pragma unroll
  for (int e = 0; e < EPK; e++) {
    if (snbr[kk + e * NW] >= 0) {
#pragma unroll
      for (int q = 0; q < CC; q++) m[q] = fmaxf(m[q], acc[e][q]);
    }
  }
#pragma unroll
  for (int q = 0; q < CC; q++) sRed[kk * C + cc + q * 64] = m[q];
  __syncthreads();
  if (kk == 0) {
#pragma unroll
    for (int q = 0; q < CC; q++) {
      const int c = cc + q * 64;
      float mm = sRed[c];
#pragma unroll
      for (int w2 = 1; w2 < NW; w2++) mm = fmaxf(mm, sRed[w2 * C + c]);
      const float o = (mm > -5e8f) ? (mm + b2[c]) : -1e9f;
      const float r = fmaxf(o, 0.f);
      if (FOLDMAX) {
        atomicMax((int*)&out[b * C + c], __float_as_int(r));  // r >= 0
      } else {
        out[((size_t)b * N + i) * C + c] = r;
      }
    }
  }
}

// ---------------- stage kernels (distinct names for profiling) --------------
template<int N, int NOUT, int H, int C, bool HASX, int SMSIZE>
__device__ __forceinline__ void stage_fused_impl(
    const float* pos, double rr, int* fi, const float* U, const float* Wrel,
    const float* b1, const float* W2, const float* b2, float* out, char* sm) {
  if (blockIdx.x < NB) {
    fps_body<N, NOUT, 512>(sm, pos + (size_t)blockIdx.x * N * 3, fi, blockIdx.x);
  } else {
    const int row = blockIdx.x - NB;
    const int b = row / N;
    const int i = row - b * N;
    knnconv_body<N, H, C, HASX, false, 512>(sm, pos + (size_t)b * N * 3, b, i,
                                            U, Wrel, b1, W2, b2, out, rr);
  }
}

__global__ __attribute__((amdgpu_waves_per_eu(2, 2))) __launch_bounds__(512, 2)
void stage1_kernel(const float* __restrict__ pos, double rr, int* __restrict__ fi,
                   const float* __restrict__ Wrel, const float* __restrict__ b1,
                   const float* __restrict__ W2, const float* __restrict__ b2,
                   float* __restrict__ out) {
  __shared__ __align__(16) char sm[82944];  // pad >80KB -> 1 blk/CU (fps isolation)
  stage_fused_impl<4096, 2048, 64, 64, false, 82944>(
      pos, rr, fi, nullptr, Wrel, b1, W2, b2, out, sm);
}

__global__ __attribute__((amdgpu_waves_per_eu(2, 2))) __launch_bounds__(512, 2)
void stage2_kernel(const float* __restrict__ pos, double rr, int* __restrict__ fi,
                   const float* __restrict__ U, const float* __restrict__ Wrel,
                   const float* __restrict__ b1, const float* __restrict__ W2,
                   const float* __restrict__ b2, float* __restrict__ out) {
  __shared__ __align__(16) char sm[39440];  // 4 blk/CU
  stage_fused_impl<2048, 512, 128, 128, true, 39440>(
      pos, rr, fi, U, Wrel, b1, W2, b2, out, sm);
}

__global__ __launch_bounds__(512)
void stage3_kernel(const float* __restrict__ pos, double rr,
                   const float* __restrict__ U, const float* __restrict__ Wrel,
                   const float* __restrict__ b1, const float* __restrict__ W2,
                   const float* __restrict__ b2, float* __restrict__ feat) {
  __shared__ __align__(16) char sm[61968];  // 2 blk/CU
  const int b = blockIdx.x / 512;
  const int i = blockIdx.x - b * 512;
  knnconv_body<512, 256, 256, true, true, 512>(sm, pos + (size_t)b * 512 * 3,
                                               b, i, U, Wrel, b1, W2, b2,
                                               feat, rr);
}

// ---------------- fused gather + preproj (U = x[fi] @ W[:CIN] + b) ----------
template<int CIN, int HH>
__global__ __launch_bounds__(HH)
void gp_kernel(const float* __restrict__ X, const float* __restrict__ posPrev,
               const int* __restrict__ fi, int Nprev, int M,
               const float* __restrict__ W, const float* __restrict__ bias,
               float* __restrict__ U, float* __restrict__ posDst) {
  const int row = blockIdx.x;
  const int b = row / M;
  const int tid = threadIdx.x;
  const int j = fi[row];
  __shared__ float sx[CIN];
  if (tid < CIN) sx[tid] = X[((size_t)b * Nprev + j) * CIN + tid];
  if (tid < 3) posDst[(size_t)row * 3 + tid] = posPrev[((size_t)b * Nprev + j) * 3 + tid];
  __syncthreads();
  float a = bias[tid];
  for (int f = 0; f < CIN; f++) a = fmaf(sx[f], W[f * HH + tid], a);
  U[(size_t)row * HH + tid] = a;
}

// ---------------- classifier/defense heads (feat precomputed) ---------------
__global__ __launch_bounds__(256) void head_kernel(
    const float* __restrict__ feat,
    const float* __restrict__ Wc1, const float* __restrict__ bc1,
    const float* __restrict__ Wc2, const float* __restrict__ bc2,
    const float* __restrict__ Wc3, const float* __restrict__ bc3,
    const float* __restrict__ Wd1, const float* __restrict__ bd1,
    const float* __restrict__ Wd2, const float* __restrict__ bd2,
    float* __restrict__ out) {
  const int b = blockIdx.x, tid = threadIdx.x;
  __shared__ float sf[256], sh[256], sh2[256], shd[256], sl[48];
  sf[tid] = feat[b * 256 + tid];
  __syncthreads();
  float a = bc1[tid], ad = bd1[tid];
  for (int f = 0; f < 256; f++) {
    const float fv = sf[f];
    a  = fmaf(fv, Wc1[f * 256 + tid], a);
    ad = fmaf(fv, Wd1[f * 256 + tid], ad);
  }
  sh[tid] = fmaxf(a, 0.f);
  shd[tid] = fmaxf(ad, 0.f);
  __syncthreads();
  float a2 = bc2[tid];
  for (int f = 0; f < 256; f++) a2 = fmaf(sh[f], Wc2[f * 256 + tid], a2);
  sh2[tid] = fmaxf(a2, 0.f);
  __syncthreads();
  if (tid < 40) {
    float l = bc3[tid];
    for (int f = 0; f < 256; f++) l = fmaf(sh2[f], Wc3[f * 40 + tid], l);
    sl[tid] = l;
  }
  if (tid >= 64 && tid < 66) {
    const int q = tid - 64;
    float l = bd2[q];
    for (int f = 0; f < 256; f++) l = fmaf(shd[f], Wd2[f * 2 + q], l);
    sl[40 + q] = l;
  }
  __syncthreads();
  if (tid == 0) {
    float m0 = sl[0];
    for (int q = 1; q < 40; q++) m0 = fmaxf(m0, sl[q]);
    float s = 0.f;
    for (int q = 0; q < 40; q++) s += expf(sl[q] - m0);
    const float ls = logf(s);
    for (int q = 0; q < 40; q++) out[b * 40 + q] = sl[q] - m0 - ls;
    const float m1 = fmaxf(sl[40], sl[41]);
    const float s1 = expf(sl[40] - m1) + expf(sl[41] - m1);
    const float ls1 = logf(s1);
    out[320 + b * 2 + 0] = sl[40] - m1 - ls1;
    out[320 + b * 2 + 1] = sl[41] - m1 - ls1;
  }
}

// ---------------------------------------------------------------------------
extern "C" void kernel_launch(void* const* d_in, const int* in_sizes, int n_in,
                              void* d_out, int out_size, void* d_ws, size_t ws_size,
                              hipStream_t stream) {
  (void)in_sizes; (void)n_in; (void)out_size; (void)ws_size;
  const float* pos = (const float*)d_in[0];
  const float* W1a = (const float*)d_in[1];  const float* b1a = (const float*)d_in[2];
  const float* W1b = (const float*)d_in[3];  const float* b1b = (const float*)d_in[4];
  const float* W2a = (const float*)d_in[5];  const float* b2a = (const float*)d_in[6];
  const float* W2b = (const float*)d_in[7];  const float* b2b = (const float*)d_in[8];
  const float* W3a = (const float*)d_in[9];  const float* b3a = (const float*)d_in[10];
  const float* W3b = (const float*)d_in[11]; const float* b3b = (const float*)d_in[12];
  const float* Wc1 = (const float*)d_in[13]; const float* bc1 = (const float*)d_in[14];
  const float* Wc2 = (const float*)d_in[15]; const float* bc2 = (const float*)d_in[16];
  const float* Wc3 = (const float*)d_in[17]; const float* bc3 = (const float*)d_in[18];
  const float* Wd1 = (const float*)d_in[19]; const float* bd1 = (const float*)d_in[20];
  const float* Wd2 = (const float*)d_in[21]; const float* bd2 = (const float*)d_in[22];
  float* out = (float*)d_out;

  char* w = (char*)d_ws;
  auto alloc = [&](size_t bytes) -> void* {
    void* p = (void*)w;
    w += (bytes + 255) & ~(size_t)255;
    return p;
  };
  int*   fi1  = (int*)  alloc((size_t)NB*2048*4);
  float* x1   = (float*)alloc((size_t)NB*4096*64*4);
  float* pos2 = (float*)alloc((size_t)NB*2048*3*4);
  float* U2   = (float*)alloc((size_t)NB*2048*128*4);
  float* x2   = (float*)alloc((size_t)NB*2048*128*4);
  int*   fi2  = (int*)  alloc((size_t)NB*512*4);
  float* pos3 = (float*)alloc((size_t)NB*512*3*4);
  float* U3   = (float*)alloc((size_t)NB*512*256*4);
  float* feat = (float*)alloc((size_t)NB*256*4);

  // feat = 0 (atomicMax target; all pooled values are >= 0 post-relu)
  hipMemsetAsync(feat, 0, (size_t)NB * 256 * 4, stream);

  // stage 1: {fps1 || knn1+conv1}  (both depend only on pos)
  stage1_kernel<<<NB + NB * 4096, 512, 0, stream>>>(
      pos, 0.2 * 0.2, fi1, W1a, b1a, W1b, b1b, x1);

  // gather1 + preproj2 (U2 = x1[fi1] @ W2a[:64] + b2a)
  gp_kernel<64, 128><<<NB * 2048, 128, 0, stream>>>(
      x1, pos, fi1, 4096, 2048, W2a, b2a, U2, pos2);

  // stage 2: {fps2 || knn2+conv2}
  stage2_kernel<<<NB + NB * 2048, 512, 0, stream>>>(
      pos2, 0.4 * 0.4, fi2, U2, W2a + (size_t)64 * 128, b2a, W2b, b2b, x2);

  // gather2 + preproj3
  gp_kernel<128, 256><<<NB * 512, 256, 0, stream>>>(
      x2, pos2, fi2, 2048, 512, W3a, b3a, U3, pos3);

  // stage 3: knn3+conv3 with fused global max-pool (atomicMax into feat)
  stage3_kernel<<<NB * 512, 512, 0, stream>>>(
      pos3, 1.0, U3, W3a + (size_t)128 * 256, b3a, W3b, b3b, feat);

  // heads
  head_kernel<<<NB, 256, 0, stream>>>(feat, Wc1, bc1, Wc2, bc2, Wc3, bc3,
                                      Wd1, bd1, Wd2, bd2, out);
}